// Round 6
// baseline (353.191 us; speedup 1.0000x reference)
//
#include <hip/hip_runtime.h>

#define B_ 512
#define L_ 512
#define N_ 128
#define TM 256          // boundary: fwd produces alpha_255, bwd produces beta_255
#define C_BIAS 3.0f

typedef _Float16 h2_t __attribute__((ext_vector_type(2)));
typedef _Float16 h8_t __attribute__((ext_vector_type(8)));
typedef float    f4_t __attribute__((ext_vector_type(4)));

// ---- full-rate VALU wave-64 reductions via DPP (no ds_swizzle chains) ----
#define DPP_STEP_MAX(v, ctrl)                                                   \
    {                                                                           \
        int _t = __builtin_amdgcn_update_dpp(__float_as_int(v),                 \
                    __float_as_int(v), ctrl, 0xf, 0xf, false);                  \
        v = fmaxf(v, __int_as_float(_t));                                       \
    }
#define DPP_STEP_ADD(v, ctrl)                                                   \
    {                                                                           \
        int _t = __builtin_amdgcn_update_dpp(__float_as_int(v),                 \
                    __float_as_int(v), ctrl, 0xf, 0xf, false);                  \
        v = v + __int_as_float(_t);                                             \
    }

__device__ __forceinline__ float wave_max(float v) {
    DPP_STEP_MAX(v, 0xB1);   // quad_perm [1,0,3,2]
    DPP_STEP_MAX(v, 0x4E);   // quad_perm [2,3,0,1]
    DPP_STEP_MAX(v, 0x141);  // row_half_mirror
    DPP_STEP_MAX(v, 0x140);  // row_mirror
    DPP_STEP_MAX(v, 0x142);  // row_bcast15
    DPP_STEP_MAX(v, 0x143);  // row_bcast31
    return __int_as_float(__builtin_amdgcn_readlane(__float_as_int(v), 63));
}
__device__ __forceinline__ float wave_sum(float v) {
    DPP_STEP_ADD(v, 0xB1);
    DPP_STEP_ADD(v, 0x4E);
    DPP_STEP_ADD(v, 0x141);
    DPP_STEP_ADD(v, 0x140);
    DPP_STEP_ADD(v, 0x142);  // lane63 path stays exact; other lanes don't matter
    DPP_STEP_ADD(v, 0x143);
    return __int_as_float(__builtin_amdgcn_readlane(__float_as_int(v), 63));
}

// One j-tile chain: 4 MFMAs over the K slices, ks ascending (same accumulation
// order as R3/R5 → bit-identical results). Intrinsics only.
#define CHAIN4(qv, BT)                                                          \
    f4_t qv = __builtin_amdgcn_mfma_f32_16x16x32_f16(A0, BT[0], z, 0, 0, 0);    \
    qv = __builtin_amdgcn_mfma_f32_16x16x32_f16(A1, BT[1], qv, 0, 0, 0);        \
    qv = __builtin_amdgcn_mfma_f32_16x16x32_f16(A2, BT[2], qv, 0, 0, 0);        \
    qv = __builtin_amdgcn_mfma_f32_16x16x32_f16(A3, BT[3], qv, 0, 0, 0);

// ---------------------------------------------------------------------------
// norm_kernel: 128 blocks x 512 threads = 8 waves/block = 2 waves/SIMD on
// 128 CUs. Each wave runs ONE chain (batch 4*blk + (w>>1), dir w&1) fully
// independently — barrier-free, wave-synchronous, private LDS slice. The two
// co-resident waves per SIMD fill each other's stalls (R5 had MfmaUtil+VALU
// = 64% with ~35% dead issue slots at 1 wave/SIMD; R2's cross-wave split
// failed because it bought TLP with a per-step barrier — this buys the same
// TLP with zero coupling, at the cost of half the CUs idle).
// Per-wave math identical to R5: matvec on the matrix pipe (8 j-tiles x 4
// K-slices of mfma_16x16x32_f16, A = E replicated over rows from LDS, B =
// static exp(trans) fragments), in-register pickup (lane l owns states
// s0 = 32*(l>>4) + (l&15), s1 = s0+16), lagged DPP max, C_BIAS.
// ---------------------------------------------------------------------------
__global__ __launch_bounds__(512, 2) void norm_kernel(
    const float* __restrict__ em, const int* __restrict__ tg,
    const float* __restrict__ mask, const float* __restrict__ st,
    const float* __restrict__ trans,
    float* __restrict__ alpha, float* __restrict__ beta,
    float* __restrict__ pathf, float* __restrict__ pathb)
{
    __shared__ __align__(16) _Float16 EhA[8][128];   // per-wave E/F vector
    __shared__ float MldsA[8][256];                  // per-wave mask row half

    const int tid = threadIdx.x;
    const int l  = tid & 63;
    const int w  = tid >> 6;
    _Float16* __restrict__ Eh   = &EhA[w][0];
    float*    __restrict__ Mlds = &MldsA[w][0];

    const int c  = l & 15;       // MFMA n-index (D col)
    const int h  = l >> 4;       // MFMA k-group
    const int s0 = 32 * h + c;   // owned state 0  (j-tile 2h)
    const int s1 = s0 + 16;      // owned state 1  (j-tile 2h+1)
    const bool hb0 = (h & 1) != 0;
    const bool hb1 = (h & 2) != 0;
    const int b  = blockIdx.x * 4 + (w >> 1);
    const int bw = w & 1;
    const size_t base = (size_t)b * L_ * N_;
    const int bL = b * L_;

    if (bw == 0) {
        // ================= FORWARD =================
        // path-score half: t in [1, TM)
        float pacc = 0.f;
        for (int t = 1 + l; t < TM; t += 64) {
            int cur  = tg[bL + t];
            int prev = tg[bL + t - 1];
            pacc += mask[bL + t] * (trans[prev * N_ + cur] + em[base + (size_t)t * N_ + cur]);
        }
        pacc = wave_sum(pacc);
        if (l == 0) {
            int t0 = tg[bL];
            pathf[b] = pacc + st[t0] + em[base + t0];
        }

#pragma unroll
        for (int k = 0; k < 4; ++k) Mlds[l + 64 * k] = mask[bL + l + 64 * k];

        // B-fragments: Bf[jt][ks][e] = exp(trans[32ks + 8h + e][16jt + c])
        h8_t Bf[8][4];
#pragma unroll
        for (int jt = 0; jt < 8; ++jt)
#pragma unroll
            for (int ks = 0; ks < 4; ++ks) {
                h8_t f;
#pragma unroll
                for (int e = 0; e < 8; ++e)
                    f[e] = (_Float16)__expf(trans[(32 * ks + 8 * h + e) * N_ + 16 * jt + c]);
                Bf[jt][ks] = f;
            }

        // init alpha_0
        float ns0 = st[s0] + em[base + s0];
        float ns1 = st[s1] + em[base + s1];
        float Mprev = wave_max(fmaxf(ns0, ns1));
        Eh[s0] = (_Float16)__expf(ns0 - Mprev - C_BIAS);
        Eh[s1] = (_Float16)__expf(ns1 - Mprev - C_BIAS);

        float pa0 = em[base + (size_t)1 * N_ + s0], pb0 = em[base + (size_t)1 * N_ + s1];
        float pa1 = em[base + (size_t)2 * N_ + s0], pb1 = em[base + (size_t)2 * N_ + s1];
        float pa2 = em[base + (size_t)3 * N_ + s0], pb2 = em[base + (size_t)3 * N_ + s1];
        float pa3 = em[base + (size_t)4 * N_ + s0], pb3 = em[base + (size_t)4 * N_ + s1];

        auto step = [&](int t, float& sa, float& sb) {
            float emv0 = sa, emv1 = sb;
            int tpf = t + 4; if (tpf > TM - 1) tpf = TM - 1;
            sa = em[base + (size_t)tpf * N_ + s0];
            sb = em[base + (size_t)tpf * N_ + s1];
            float mk = Mlds[t];

            float mx = wave_max(fmaxf(ns0, ns1));   // max(ns_{t-1}); overlaps MFMA

            // A-fragments: E[32ks + 8h + e] — row-uniform broadcast reads
            const _Float16* Eb = (const _Float16*)Eh;
            h8_t A0 = *(const h8_t*)(Eb + 8 * h);
            h8_t A1 = *(const h8_t*)(Eb + 32 + 8 * h);
            h8_t A2 = *(const h8_t*)(Eb + 64 + 8 * h);
            h8_t A3 = *(const h8_t*)(Eb + 96 + 8 * h);

            f4_t z = {0.f, 0.f, 0.f, 0.f};
            CHAIN4(q0, Bf[0]) CHAIN4(q1, Bf[1]) CHAIN4(q2, Bf[2]) CHAIN4(q3, Bf[3])
            CHAIN4(q4, Bf[4]) CHAIN4(q5, Bf[5]) CHAIN4(q6, Bf[6]) CHAIN4(q7, Bf[7])

            // in-register pickup of owned states (replicated D rows, reg 0)
            float sv0 = hb1 ? (hb0 ? q6[0] : q4[0]) : (hb0 ? q2[0] : q0[0]);
            float sv1 = hb1 ? (hb0 ? q7[0] : q5[0]) : (hb0 ? q3[0] : q1[0]);

            float badd = Mprev + C_BIAS;
            float nxt0 = __logf(sv0) + badd + emv0;
            float nxt1 = __logf(sv1) + badd + emv1;
            float im = 1.f - mk;
            ns0 = mk * nxt0 + im * ns0;
            ns1 = mk * nxt1 + im * ns1;

            Mprev = mx;
            Eh[s0] = (_Float16)__expf(ns0 - mx - C_BIAS);
            Eh[s1] = (_Float16)__expf(ns1 - mx - C_BIAS);
        };

        for (int tt = 1; tt + 3 < TM; tt += 4) {
            step(tt    , pa0, pb0);
            step(tt + 1, pa1, pb1);
            step(tt + 2, pa2, pb2);
            step(tt + 3, pa3, pb3);
        }
        step(TM - 3, pa0, pb0);
        step(TM - 2, pa1, pb1);
        step(TM - 1, pa2, pb2);

        alpha[b * N_ + s0] = ns0;
        alpha[b * N_ + s1] = ns1;
    } else {
        // ================= BACKWARD =================
        // path-score half: t in [TM, L)
        float pacc = 0.f;
        for (int t = TM + l; t < L_; t += 64) {
            int cur  = tg[bL + t];
            int prev = tg[bL + t - 1];
            pacc += mask[bL + t] * (trans[prev * N_ + cur] + em[base + (size_t)t * N_ + cur]);
        }
        pacc = wave_sum(pacc);
        if (l == 0) pathb[b] = pacc;

#pragma unroll
        for (int k = 0; k < 4; ++k) Mlds[l + 64 * k] = mask[bL + TM + l + 64 * k];

        // B-fragments: Bf[it][ks][e] = exp(trans[16it + c][32ks + 8h + e])
        h8_t Bf[8][4];
#pragma unroll
        for (int it = 0; it < 8; ++it)
#pragma unroll
            for (int ks = 0; ks < 4; ++ks) {
                const float* p = trans + (size_t)(16 * it + c) * N_ + 32 * ks + 8 * h;
                float4 q0 = *(const float4*)p;
                float4 q1 = *(const float4*)(p + 4);
                h8_t f;
                f[0] = (_Float16)__expf(q0.x); f[1] = (_Float16)__expf(q0.y);
                f[2] = (_Float16)__expf(q0.z); f[3] = (_Float16)__expf(q0.w);
                f[4] = (_Float16)__expf(q1.x); f[5] = (_Float16)__expf(q1.y);
                f[6] = (_Float16)__expf(q1.z); f[7] = (_Float16)__expf(q1.w);
                Bf[it][ks] = f;
            }

        // init at u=511: beta_511 = 0 ; v = beta + em_511
        float b0 = 0.f, b1 = 0.f;
        float v0 = em[base + (size_t)(L_ - 1) * N_ + s0];
        float v1 = em[base + (size_t)(L_ - 1) * N_ + s1];
        float Mprev = wave_max(fmaxf(v0, v1));
        Eh[s0] = (_Float16)__expf(v0 - Mprev - C_BIAS);
        Eh[s1] = (_Float16)__expf(v1 - Mprev - C_BIAS);

        float pa0 = em[base + (size_t)510 * N_ + s0], pb0 = em[base + (size_t)510 * N_ + s1];
        float pa1 = em[base + (size_t)509 * N_ + s0], pb1 = em[base + (size_t)509 * N_ + s1];
        float pa2 = em[base + (size_t)508 * N_ + s0], pb2 = em[base + (size_t)508 * N_ + s1];
        float pa3 = em[base + (size_t)507 * N_ + s0], pb3 = em[base + (size_t)507 * N_ + s1];

        // iter t (510 down to 255): consumes F_{t+1} (Eh), em_t (pipe), mask_{t+1}
        auto step = [&](int t, float& sa, float& sb) {
            float emt0 = sa, emt1 = sb;
            int tpf = t - 4; if (tpf < TM - 1) tpf = TM - 1;
            sa = em[base + (size_t)tpf * N_ + s0];
            sb = em[base + (size_t)tpf * N_ + s1];
            float mk = Mlds[t + 1 - TM];

            float mx = wave_max(fmaxf(v0, v1));   // max(v_{t+1}); overlaps MFMA

            const _Float16* Fb = (const _Float16*)Eh;
            h8_t A0 = *(const h8_t*)(Fb + 8 * h);
            h8_t A1 = *(const h8_t*)(Fb + 32 + 8 * h);
            h8_t A2 = *(const h8_t*)(Fb + 64 + 8 * h);
            h8_t A3 = *(const h8_t*)(Fb + 96 + 8 * h);

            f4_t z = {0.f, 0.f, 0.f, 0.f};
            CHAIN4(q0, Bf[0]) CHAIN4(q1, Bf[1]) CHAIN4(q2, Bf[2]) CHAIN4(q3, Bf[3])
            CHAIN4(q4, Bf[4]) CHAIN4(q5, Bf[5]) CHAIN4(q6, Bf[6]) CHAIN4(q7, Bf[7])

            float sv0 = hb1 ? (hb0 ? q6[0] : q4[0]) : (hb0 ? q2[0] : q0[0]);
            float sv1 = hb1 ? (hb0 ? q7[0] : q5[0]) : (hb0 ? q3[0] : q1[0]);

            float badd = Mprev + C_BIAS;
            float upd0 = __logf(sv0) + badd;
            float upd1 = __logf(sv1) + badd;
            float im = 1.f - mk;
            b0 = mk * upd0 + im * b0;
            b1 = mk * upd1 + im * b1;

            v0 = b0 + emt0;
            v1 = b1 + emt1;
            Mprev = mx;
            Eh[s0] = (_Float16)__expf(v0 - mx - C_BIAS);
            Eh[s1] = (_Float16)__expf(v1 - mx - C_BIAS);
        };

        for (int tt = 510; tt >= 258; tt -= 4) {   // 64 groups x 4 = t 510..255
            step(tt    , pa0, pb0);
            step(tt - 1, pa1, pb1);
            step(tt - 2, pa2, pb2);
            step(tt - 3, pa3, pb3);
        }

        beta[b * N_ + s0] = b0;
        beta[b * N_ + s1] = b1;
    }
}

// ---------------------------------------------------------------------------
// zres_kernel: 512 blocks x 1 wave. Block b: zres[b] = LSE_j(alpha[j]+beta[j])
//              - pathf[b] - pathb[b].
// ---------------------------------------------------------------------------
__global__ __launch_bounds__(64) void zres_kernel(
    const float* __restrict__ alpha, const float* __restrict__ beta,
    const float* __restrict__ pathf, const float* __restrict__ pathb,
    float* __restrict__ zres)
{
    const int l = threadIdx.x;
    const int b = blockIdx.x;
    float2 av = *(const float2*)(alpha + b * N_ + 2 * l);
    float2 bv = *(const float2*)(beta  + b * N_ + 2 * l);
    float v0 = av.x + bv.x;
    float v1 = av.y + bv.y;
    float m = wave_max(fmaxf(v0, v1));
    float s = wave_sum(__expf(v0 - m) + __expf(v1 - m));
    if (l == 0) zres[b] = m + __logf(s) - pathf[b] - pathb[b];
}

// ---------------------------------------------------------------------------
// mean_kernel: 1 wave. out = mean(zres). 8 values/lane (2x float4) + DPP tree.
// ---------------------------------------------------------------------------
__global__ __launch_bounds__(64) void mean_kernel(
    const float* __restrict__ zres, float* __restrict__ out)
{
    const int l = threadIdx.x;
    const float4* z4 = (const float4*)zres;
    float4 a = z4[2 * l];
    float4 c = z4[2 * l + 1];
    float acc = ((a.x + a.y) + (a.z + a.w)) + ((c.x + c.y) + (c.z + c.w));
    acc = wave_sum(acc);
    if (l == 0) out[0] = acc * (1.0f / (float)B_);
}

// ---------------------------------------------------------------------------
extern "C" void kernel_launch(void* const* d_in, const int* in_sizes, int n_in,
                              void* d_out, int out_size, void* d_ws, size_t ws_size,
                              hipStream_t stream) {
    const float* emission    = (const float*)d_in[0];
    const int*   target      = (const int*)  d_in[1];
    const float* mask        = (const float*)d_in[2];
    const float* start_trans = (const float*)d_in[3];
    const float* trans       = (const float*)d_in[4];
    float* out = (float*)d_out;

    float* ws_f  = (float*)d_ws;
    float* alpha = ws_f;                        // 512*128
    float* beta  = ws_f + B_ * N_;              // 512*128
    float* pathf = ws_f + 2 * B_ * N_;          // 512
    float* pathb = ws_f + 2 * B_ * N_ + B_;     // 512
    float* zres  = ws_f + 2 * B_ * N_ + 2 * B_; // 512

    norm_kernel<<<B_ / 4, 512, 0, stream>>>(emission, target, mask, start_trans,
                                            trans, alpha, beta, pathf, pathb);
    zres_kernel<<<B_, 64, 0, stream>>>(alpha, beta, pathf, pathb, zres);
    mean_kernel<<<1, 64, 0, stream>>>(zres, out);
}

// Round 7
// 279.899 us; speedup vs baseline: 1.2619x; 1.2619x over previous
//
#include <hip/hip_runtime.h>

#define B_ 512
#define L_ 512
#define N_ 128
#define TM 256          // boundary: fwd produces alpha_255, bwd produces beta_255
#define C_BIAS 3.0f

typedef float f4_t __attribute__((ext_vector_type(4)));
typedef int   v8i_t __attribute__((ext_vector_type(8)));

// ---- full-rate VALU wave-64 reductions via DPP (no ds_swizzle chains) ----
#define DPP_STEP_MAX(v, ctrl)                                                   \
    {                                                                           \
        int _t = __builtin_amdgcn_update_dpp(__float_as_int(v),                 \
                    __float_as_int(v), ctrl, 0xf, 0xf, false);                  \
        v = fmaxf(v, __int_as_float(_t));                                       \
    }
#define DPP_STEP_ADD(v, ctrl)                                                   \
    {                                                                           \
        int _t = __builtin_amdgcn_update_dpp(__float_as_int(v),                 \
                    __float_as_int(v), ctrl, 0xf, 0xf, false);                  \
        v = v + __int_as_float(_t);                                             \
    }

__device__ __forceinline__ float wave_max(float v) {
    DPP_STEP_MAX(v, 0xB1);   // quad_perm [1,0,3,2]
    DPP_STEP_MAX(v, 0x4E);   // quad_perm [2,3,0,1]
    DPP_STEP_MAX(v, 0x141);  // row_half_mirror
    DPP_STEP_MAX(v, 0x140);  // row_mirror
    DPP_STEP_MAX(v, 0x142);  // row_bcast15
    DPP_STEP_MAX(v, 0x143);  // row_bcast31
    return __int_as_float(__builtin_amdgcn_readlane(__float_as_int(v), 63));
}
__device__ __forceinline__ float wave_sum(float v) {
    DPP_STEP_ADD(v, 0xB1);
    DPP_STEP_ADD(v, 0x4E);
    DPP_STEP_ADD(v, 0x141);
    DPP_STEP_ADD(v, 0x140);
    DPP_STEP_ADD(v, 0x142);  // lane63 path stays exact; other lanes don't matter
    DPP_STEP_ADD(v, 0x143);
    return __int_as_float(__builtin_amdgcn_readlane(__float_as_int(v), 63));
}

// ---- fp8 (OCP e4m3fn) packing helpers ----
#if __has_builtin(__builtin_amdgcn_cvt_pk_fp8_f32)
__device__ __forceinline__ unsigned fp8_pair(float a, float b) {
    // byte0 = fp8(a), byte1 = fp8(b) in word0
    return (unsigned)__builtin_amdgcn_cvt_pk_fp8_f32(a, b, 0, false);
}
__device__ __forceinline__ unsigned fp8_quad(float a, float b, float c, float d) {
    int lo = __builtin_amdgcn_cvt_pk_fp8_f32(a, b, 0, false);
    return (unsigned)__builtin_amdgcn_cvt_pk_fp8_f32(c, d, lo, true);
}
#else
__device__ __forceinline__ unsigned char f32_e4m3(float v) {
    if (!(v > 0.f)) return 0;                 // inputs here are always >= 0
    if (v >= 448.f) return 0x7E;              // clamp to max finite
    if (v < 0.015625f) {                      // denormal grid: m * 2^-9
        int m = (int)(v * 512.f + 0.5f);
        return (unsigned char)m;              // m==8 rolls into first normal: ok
    }
    union { float f; unsigned u; } x; x.f = v;
    unsigned u = x.u;
    unsigned lsb = (u >> 20) & 1;
    u += 0x0007FFFF + lsb;                    // RNE to 3 mantissa bits
    int e = (int)((u >> 23) & 255) - 127 + 7; // rebias to e4
    unsigned m = (u >> 20) & 7;
    if (e > 15) return 0x7E;
    return (unsigned char)((e << 3) | m);
}
__device__ __forceinline__ unsigned fp8_pair(float a, float b) {
    return (unsigned)f32_e4m3(a) | ((unsigned)f32_e4m3(b) << 8);
}
__device__ __forceinline__ unsigned fp8_quad(float a, float b, float c, float d) {
    return fp8_pair(a, b) | (fp8_pair(c, d) << 16);
}
#endif

#define SCALE_ONE 0x7F7F7F7F   // every e8m0 byte = 2^0: scale-layout-proof

// One j-tile: FULL K=128 contraction in a single MX MFMA (replaces R5's
// 4-deep 16x16x32 chain). cbsz=0/blgp=0 = fp8(e4m3) for both operands.
#define MXMFMA(qv, bt)                                                          \
    f4_t qv = __builtin_amdgcn_mfma_scale_f32_16x16x128_f8f6f4(                 \
        Afrag, bt, z, 0, 0, 0, SCALE_ONE, 0, SCALE_ONE);

// ---------------------------------------------------------------------------
// norm_kernel: 1024 blocks x 64 threads (1 wave) = 1 wave/SIMD (R5 geometry —
// R6 proved 2 waves/SIMD on half the CUs is a net loss). Per step the 128-wide
// LSE matvec runs as 8 INDEPENDENT mfma_scale_f32_16x16x128_f8f6f4 (one per
// 16-wide j-tile, full K=128 each) — 4x fewer matrix-pipe cycles than R5's
// 32x 16x16x32_f16 (the pipe is CU-shared by the 4 resident waves).
//   A = E vector as fp8, replicated over the 16 rows: lane l reads bytes
//       E[32*(l>>4) .. +32) from LDS (2x ds_read_b128, row-uniform broadcast).
//   B = static fp8(exp(trans)) fragments, 8x v8i_t = 64 VGPRs (was 128).
//   Scales = 0x7F7F7F7F (all 2^0) -> layout-agnostic. A row-replication +
//   identical (group,byte)->k map on A and B makes the contraction invariant
//   to the true k-permutation. D layout = 16x16 family: col=lane&15, rows
//   replicated -> in-register pickup identical to R5 (lane owns s0=32h+c,
//   s1=s0+16). Lagged DPP max + C_BIAS=3 keep E <= ~e^5 << 448 (fp8 max).
// ---------------------------------------------------------------------------
__global__ __launch_bounds__(64, 1) void norm_kernel(
    const float* __restrict__ em, const int* __restrict__ tg,
    const float* __restrict__ mask, const float* __restrict__ st,
    const float* __restrict__ trans,
    float* __restrict__ alpha, float* __restrict__ beta,
    float* __restrict__ pathf, float* __restrict__ pathb)
{
    __shared__ __align__(32) unsigned char Eh[128];  // E/F vector, fp8 e4m3
    __shared__ float Mlds[TM];                       // mask row half

    const int l  = threadIdx.x;
    const int c  = l & 15;       // MFMA n-index (D col)
    const int h  = l >> 4;       // MFMA k-group (32 bytes per group)
    const int s0 = 32 * h + c;   // owned state 0  (j-tile 2h)
    const int s1 = s0 + 16;      // owned state 1  (j-tile 2h+1)
    const bool hb0 = (h & 1) != 0;
    const bool hb1 = (h & 2) != 0;
    const int b  = blockIdx.x >> 1;
    const int bw = blockIdx.x & 1;
    const size_t base = (size_t)b * L_ * N_;
    const int bL = b * L_;

    if (bw == 0) {
        // ================= FORWARD =================
        // path-score half: t in [1, TM)
        float pacc = 0.f;
        for (int t = 1 + l; t < TM; t += 64) {
            int cur  = tg[bL + t];
            int prev = tg[bL + t - 1];
            pacc += mask[bL + t] * (trans[prev * N_ + cur] + em[base + (size_t)t * N_ + cur]);
        }
        pacc = wave_sum(pacc);
        if (l == 0) {
            int t0 = tg[bL];
            pathf[b] = pacc + st[t0] + em[base + t0];
        }

#pragma unroll
        for (int k = 0; k < 4; ++k) Mlds[l + 64 * k] = mask[bL + l + 64 * k];

        // B-fragments: Bf[jt] byte e = fp8(exp(trans[32h + e][16jt + c]))
        v8i_t Bf[8];
#pragma unroll
        for (int jt = 0; jt < 8; ++jt) {
            v8i_t bb;
#pragma unroll
            for (int dd = 0; dd < 8; ++dd) {
                const float* p = trans + (size_t)(32 * h + 4 * dd) * N_ + 16 * jt + c;
                float f0 = __expf(p[0]);
                float f1 = __expf(p[N_]);
                float f2 = __expf(p[2 * N_]);
                float f3 = __expf(p[3 * N_]);
                bb[dd] = (int)fp8_quad(f0, f1, f2, f3);
            }
            Bf[jt] = bb;
        }

        // init alpha_0
        float ns0 = st[s0] + em[base + s0];
        float ns1 = st[s1] + em[base + s1];
        float Mprev = wave_max(fmaxf(ns0, ns1));
        {
            unsigned p = fp8_pair(__expf(ns0 - Mprev - C_BIAS), __expf(ns1 - Mprev - C_BIAS));
            Eh[s0] = (unsigned char)(p & 0xFF);
            Eh[s1] = (unsigned char)((p >> 8) & 0xFF);
        }

        float pa0 = em[base + (size_t)1 * N_ + s0], pb0 = em[base + (size_t)1 * N_ + s1];
        float pa1 = em[base + (size_t)2 * N_ + s0], pb1 = em[base + (size_t)2 * N_ + s1];
        float pa2 = em[base + (size_t)3 * N_ + s0], pb2 = em[base + (size_t)3 * N_ + s1];
        float pa3 = em[base + (size_t)4 * N_ + s0], pb3 = em[base + (size_t)4 * N_ + s1];

        auto step = [&](int t, float& sa, float& sb) {
            float emv0 = sa, emv1 = sb;
            int tpf = t + 4; if (tpf > TM - 1) tpf = TM - 1;
            sa = em[base + (size_t)tpf * N_ + s0];
            sb = em[base + (size_t)tpf * N_ + s1];
            float mk = Mlds[t];

            float mx = wave_max(fmaxf(ns0, ns1));   // max(ns_{t-1}); overlaps MFMA

            // A-fragment: 32 fp8 bytes E[32h .. 32h+32), row-uniform broadcast
            v8i_t Afrag = *(const v8i_t*)(Eh + 32 * h);

            f4_t z = {0.f, 0.f, 0.f, 0.f};
            MXMFMA(q0, Bf[0]) MXMFMA(q1, Bf[1]) MXMFMA(q2, Bf[2]) MXMFMA(q3, Bf[3])
            MXMFMA(q4, Bf[4]) MXMFMA(q5, Bf[5]) MXMFMA(q6, Bf[6]) MXMFMA(q7, Bf[7])

            // in-register pickup of owned states (replicated D rows, reg 0)
            float sv0 = hb1 ? (hb0 ? q6[0] : q4[0]) : (hb0 ? q2[0] : q0[0]);
            float sv1 = hb1 ? (hb0 ? q7[0] : q5[0]) : (hb0 ? q3[0] : q1[0]);

            float badd = Mprev + C_BIAS;
            float nxt0 = __logf(sv0) + badd + emv0;
            float nxt1 = __logf(sv1) + badd + emv1;
            float im = 1.f - mk;
            ns0 = mk * nxt0 + im * ns0;
            ns1 = mk * nxt1 + im * ns1;

            Mprev = mx;
            unsigned p = fp8_pair(__expf(ns0 - mx - C_BIAS), __expf(ns1 - mx - C_BIAS));
            Eh[s0] = (unsigned char)(p & 0xFF);
            Eh[s1] = (unsigned char)((p >> 8) & 0xFF);
        };

        for (int tt = 1; tt + 3 < TM; tt += 4) {
            step(tt    , pa0, pb0);
            step(tt + 1, pa1, pb1);
            step(tt + 2, pa2, pb2);
            step(tt + 3, pa3, pb3);
        }
        step(TM - 3, pa0, pb0);
        step(TM - 2, pa1, pb1);
        step(TM - 1, pa2, pb2);

        alpha[b * N_ + s0] = ns0;
        alpha[b * N_ + s1] = ns1;
    } else {
        // ================= BACKWARD =================
        // path-score half: t in [TM, L)
        float pacc = 0.f;
        for (int t = TM + l; t < L_; t += 64) {
            int cur  = tg[bL + t];
            int prev = tg[bL + t - 1];
            pacc += mask[bL + t] * (trans[prev * N_ + cur] + em[base + (size_t)t * N_ + cur]);
        }
        pacc = wave_sum(pacc);
        if (l == 0) pathb[b] = pacc;

#pragma unroll
        for (int k = 0; k < 4; ++k) Mlds[l + 64 * k] = mask[bL + TM + l + 64 * k];

        // B-fragments: Bf[it] byte e = fp8(exp(trans[16it + c][32h + e]))
        v8i_t Bf[8];
#pragma unroll
        for (int it = 0; it < 8; ++it) {
            v8i_t bb;
#pragma unroll
            for (int dd = 0; dd < 8; ++dd) {
                float4 q = *(const float4*)(trans + (size_t)(16 * it + c) * N_ + 32 * h + 4 * dd);
                bb[dd] = (int)fp8_quad(__expf(q.x), __expf(q.y), __expf(q.z), __expf(q.w));
            }
            Bf[it] = bb;
        }

        // init at u=511: beta_511 = 0 ; v = beta + em_511
        float b0 = 0.f, b1 = 0.f;
        float v0 = em[base + (size_t)(L_ - 1) * N_ + s0];
        float v1 = em[base + (size_t)(L_ - 1) * N_ + s1];
        float Mprev = wave_max(fmaxf(v0, v1));
        {
            unsigned p = fp8_pair(__expf(v0 - Mprev - C_BIAS), __expf(v1 - Mprev - C_BIAS));
            Eh[s0] = (unsigned char)(p & 0xFF);
            Eh[s1] = (unsigned char)((p >> 8) & 0xFF);
        }

        float pa0 = em[base + (size_t)510 * N_ + s0], pb0 = em[base + (size_t)510 * N_ + s1];
        float pa1 = em[base + (size_t)509 * N_ + s0], pb1 = em[base + (size_t)509 * N_ + s1];
        float pa2 = em[base + (size_t)508 * N_ + s0], pb2 = em[base + (size_t)508 * N_ + s1];
        float pa3 = em[base + (size_t)507 * N_ + s0], pb3 = em[base + (size_t)507 * N_ + s1];

        // iter t (510 down to 255): consumes F_{t+1} (Eh), em_t (pipe), mask_{t+1}
        auto step = [&](int t, float& sa, float& sb) {
            float emt0 = sa, emt1 = sb;
            int tpf = t - 4; if (tpf < TM - 1) tpf = TM - 1;
            sa = em[base + (size_t)tpf * N_ + s0];
            sb = em[base + (size_t)tpf * N_ + s1];
            float mk = Mlds[t + 1 - TM];

            float mx = wave_max(fmaxf(v0, v1));   // max(v_{t+1}); overlaps MFMA

            v8i_t Afrag = *(const v8i_t*)(Eh + 32 * h);

            f4_t z = {0.f, 0.f, 0.f, 0.f};
            MXMFMA(q0, Bf[0]) MXMFMA(q1, Bf[1]) MXMFMA(q2, Bf[2]) MXMFMA(q3, Bf[3])
            MXMFMA(q4, Bf[4]) MXMFMA(q5, Bf[5]) MXMFMA(q6, Bf[6]) MXMFMA(q7, Bf[7])

            float sv0 = hb1 ? (hb0 ? q6[0] : q4[0]) : (hb0 ? q2[0] : q0[0]);
            float sv1 = hb1 ? (hb0 ? q7[0] : q5[0]) : (hb0 ? q3[0] : q1[0]);

            float badd = Mprev + C_BIAS;
            float upd0 = __logf(sv0) + badd;
            float upd1 = __logf(sv1) + badd;
            float im = 1.f - mk;
            b0 = mk * upd0 + im * b0;
            b1 = mk * upd1 + im * b1;

            v0 = b0 + emt0;
            v1 = b1 + emt1;
            Mprev = mx;
            unsigned p = fp8_pair(__expf(v0 - mx - C_BIAS), __expf(v1 - mx - C_BIAS));
            Eh[s0] = (unsigned char)(p & 0xFF);
            Eh[s1] = (unsigned char)((p >> 8) & 0xFF);
        };

        for (int tt = 510; tt >= 258; tt -= 4) {   // 64 groups x 4 = t 510..255
            step(tt    , pa0, pb0);
            step(tt - 1, pa1, pb1);
            step(tt - 2, pa2, pb2);
            step(tt - 3, pa3, pb3);
        }

        beta[b * N_ + s0] = b0;
        beta[b * N_ + s1] = b1;
    }
}

// ---------------------------------------------------------------------------
// zres_kernel: 512 blocks x 1 wave. Block b: zres[b] = LSE_j(alpha[j]+beta[j])
//              - pathf[b] - pathb[b].
// ---------------------------------------------------------------------------
__global__ __launch_bounds__(64) void zres_kernel(
    const float* __restrict__ alpha, const float* __restrict__ beta,
    const float* __restrict__ pathf, const float* __restrict__ pathb,
    float* __restrict__ zres)
{
    const int l = threadIdx.x;
    const int b = blockIdx.x;
    float2 av = *(const float2*)(alpha + b * N_ + 2 * l);
    float2 bv = *(const float2*)(beta  + b * N_ + 2 * l);
    float v0 = av.x + bv.x;
    float v1 = av.y + bv.y;
    float m = wave_max(fmaxf(v0, v1));
    float s = wave_sum(__expf(v0 - m) + __expf(v1 - m));
    if (l == 0) zres[b] = m + __logf(s) - pathf[b] - pathb[b];
}

// ---------------------------------------------------------------------------
// mean_kernel: 1 wave. out = mean(zres). 8 values/lane (2x float4) + DPP tree.
// ---------------------------------------------------------------------------
__global__ __launch_bounds__(64) void mean_kernel(
    const float* __restrict__ zres, float* __restrict__ out)
{
    const int l = threadIdx.x;
    const float4* z4 = (const float4*)zres;
    float4 a = z4[2 * l];
    float4 c = z4[2 * l + 1];
    float acc = ((a.x + a.y) + (a.z + a.w)) + ((c.x + c.y) + (c.z + c.w));
    acc = wave_sum(acc);
    if (l == 0) out[0] = acc * (1.0f / (float)B_);
}

// ---------------------------------------------------------------------------
extern "C" void kernel_launch(void* const* d_in, const int* in_sizes, int n_in,
                              void* d_out, int out_size, void* d_ws, size_t ws_size,
                              hipStream_t stream) {
    const float* emission    = (const float*)d_in[0];
    const int*   target      = (const int*)  d_in[1];
    const float* mask        = (const float*)d_in[2];
    const float* start_trans = (const float*)d_in[3];
    const float* trans       = (const float*)d_in[4];
    float* out = (float*)d_out;

    float* ws_f  = (float*)d_ws;
    float* alpha = ws_f;                        // 512*128
    float* beta  = ws_f + B_ * N_;              // 512*128
    float* pathf = ws_f + 2 * B_ * N_;          // 512
    float* pathb = ws_f + 2 * B_ * N_ + B_;     // 512
    float* zres  = ws_f + 2 * B_ * N_ + 2 * B_; // 512

    norm_kernel<<<2 * B_, 64, 0, stream>>>(emission, target, mask, start_trans,
                                           trans, alpha, beta, pathf, pathb);
    zres_kernel<<<B_, 64, 0, stream>>>(alpha, beta, pathf, pathb, zres);
    mean_kernel<<<1, 64, 0, stream>>>(zres, out);
}

// Round 8
// 277.999 us; speedup vs baseline: 1.2705x; 1.0068x over previous
//
#include <hip/hip_runtime.h>

#define B_ 512
#define L_ 512
#define N_ 128
#define TM 256          // boundary: fwd produces alpha_255, bwd produces beta_255
#define C_BIAS 3.0f

typedef float f4_t __attribute__((ext_vector_type(4)));
typedef int   v8i_t __attribute__((ext_vector_type(8)));

// ---- full-rate VALU wave-64 reductions via DPP (no ds_swizzle chains) ----
#define DPP_STEP_MAX(v, ctrl)                                                   \
    {                                                                           \
        int _t = __builtin_amdgcn_update_dpp(__float_as_int(v),                 \
                    __float_as_int(v), ctrl, 0xf, 0xf, false);                  \
        v = fmaxf(v, __int_as_float(_t));                                       \
    }
#define DPP_STEP_ADD(v, ctrl)                                                   \
    {                                                                           \
        int _t = __builtin_amdgcn_update_dpp(__float_as_int(v),                 \
                    __float_as_int(v), ctrl, 0xf, 0xf, false);                  \
        v = v + __int_as_float(_t);                                             \
    }

__device__ __forceinline__ float wave_max(float v) {
    DPP_STEP_MAX(v, 0xB1);   // quad_perm [1,0,3,2]
    DPP_STEP_MAX(v, 0x4E);   // quad_perm [2,3,0,1]
    DPP_STEP_MAX(v, 0x141);  // row_half_mirror
    DPP_STEP_MAX(v, 0x140);  // row_mirror
    DPP_STEP_MAX(v, 0x142);  // row_bcast15
    DPP_STEP_MAX(v, 0x143);  // row_bcast31
    return __int_as_float(__builtin_amdgcn_readlane(__float_as_int(v), 63));
}
__device__ __forceinline__ float wave_sum(float v) {
    DPP_STEP_ADD(v, 0xB1);
    DPP_STEP_ADD(v, 0x4E);
    DPP_STEP_ADD(v, 0x141);
    DPP_STEP_ADD(v, 0x140);
    DPP_STEP_ADD(v, 0x142);  // lane63 path stays exact; other lanes don't matter
    DPP_STEP_ADD(v, 0x143);
    return __int_as_float(__builtin_amdgcn_readlane(__float_as_int(v), 63));
}

// ---- fp8 (OCP e4m3fn) packing helpers ----
#if __has_builtin(__builtin_amdgcn_cvt_pk_fp8_f32)
__device__ __forceinline__ unsigned fp8_pair(float a, float b) {
    // byte0 = fp8(a), byte1 = fp8(b) in word0
    return (unsigned)__builtin_amdgcn_cvt_pk_fp8_f32(a, b, 0, false);
}
__device__ __forceinline__ unsigned fp8_quad(float a, float b, float c, float d) {
    int lo = __builtin_amdgcn_cvt_pk_fp8_f32(a, b, 0, false);
    return (unsigned)__builtin_amdgcn_cvt_pk_fp8_f32(c, d, lo, true);
}
#else
__device__ __forceinline__ unsigned char f32_e4m3(float v) {
    if (!(v > 0.f)) return 0;                 // inputs here are always >= 0
    if (v >= 448.f) return 0x7E;              // clamp to max finite
    if (v < 0.015625f) {                      // denormal grid: m * 2^-9
        int m = (int)(v * 512.f + 0.5f);
        return (unsigned char)m;              // m==8 rolls into first normal: ok
    }
    union { float f; unsigned u; } x; x.f = v;
    unsigned u = x.u;
    unsigned lsb = (u >> 20) & 1;
    u += 0x0007FFFF + lsb;                    // RNE to 3 mantissa bits
    int e = (int)((u >> 23) & 255) - 127 + 7; // rebias to e4
    unsigned m = (u >> 20) & 7;
    if (e > 15) return 0x7E;
    return (unsigned char)((e << 3) | m);
}
__device__ __forceinline__ unsigned fp8_pair(float a, float b) {
    return (unsigned)f32_e4m3(a) | ((unsigned)f32_e4m3(b) << 8);
}
__device__ __forceinline__ unsigned fp8_quad(float a, float b, float c, float d) {
    return fp8_pair(a, b) | (fp8_pair(c, d) << 16);
}
#endif

#define SCALE_ONE 0x7F7F7F7F   // every e8m0 byte = 2^0: scale-layout-proof

// One j-tile: FULL K=128 contraction in a single MX MFMA.
#define MXMFMA(qv, bt)                                                          \
    f4_t qv = __builtin_amdgcn_mfma_scale_f32_16x16x128_f8f6f4(                 \
        Afrag, bt, z, 0, 0, 0, SCALE_ONE, 0, SCALE_ONE);

// ---------------------------------------------------------------------------
// norm_kernel: 1024 blocks x 64 threads (1 wave) = 1 wave/SIMD. Per step the
// 128-wide LSE matvec = 8x mfma_scale_f32_16x16x128_f8f6f4 (R7 structure).
// R8 latency cuts (R7: ~600 cy/step of exposed serial stall at 1 wave/SIMD):
//  (1) EARLY A-READ: the A-fragment ds_read for step t+1 issues immediately
//      after step t's E ds_write (same-wave LDS ops are in-order, so the read
//      sees all 64 lanes' writes); the ~130 cy LDS latency hides under the
//      next step's preamble (em prefetch + Mlds + DPP max) instead of
//      sitting on the MFMA critical path.
//  (2) sigma-PERMUTED E LAYOUT: lane l stores its packed fp8 pair as ONE
//      ds_write_b16 at byte 2l (bytes [2l]=E[s0], [2l+1]=E[s1]). A-frag read
//      addresses unchanged (32B @ 32h); byte meaning sigma(h,e) =
//      32h + (e>>1) + 16*(e&1) is absorbed into the static B tables (the
//      same layout-freedom trick R7 validated with absmax 0).
// Lane l owns states s0 = 32*(l>>4) + (l&15), s1 = s0+16; in-register pickup
// from replicated D rows; lagged DPP max + C_BIAS=3 keeps E <= ~e^5 << 448.
// ---------------------------------------------------------------------------
__global__ __launch_bounds__(64, 1) void norm_kernel(
    const float* __restrict__ em, const int* __restrict__ tg,
    const float* __restrict__ mask, const float* __restrict__ st,
    const float* __restrict__ trans,
    float* __restrict__ alpha, float* __restrict__ beta,
    float* __restrict__ pathf, float* __restrict__ pathb)
{
    __shared__ __align__(32) unsigned char Eh[128];  // E/F vector, fp8, sigma layout
    __shared__ float Mlds[TM];                       // mask row half

    const int l  = threadIdx.x;
    const int c  = l & 15;       // MFMA n-index (D col)
    const int h  = l >> 4;       // MFMA k-group (32 bytes per group)
    const int s0 = 32 * h + c;   // owned state 0  (j-tile 2h)
    const int s1 = s0 + 16;      // owned state 1  (j-tile 2h+1)
    const bool hb0 = (h & 1) != 0;
    const bool hb1 = (h & 2) != 0;
    const int b  = blockIdx.x >> 1;
    const int bw = blockIdx.x & 1;
    const size_t base = (size_t)b * L_ * N_;
    const int bL = b * L_;

    if (bw == 0) {
        // ================= FORWARD =================
        // path-score half: t in [1, TM)
        float pacc = 0.f;
        for (int t = 1 + l; t < TM; t += 64) {
            int cur  = tg[bL + t];
            int prev = tg[bL + t - 1];
            pacc += mask[bL + t] * (trans[prev * N_ + cur] + em[base + (size_t)t * N_ + cur]);
        }
        pacc = wave_sum(pacc);
        if (l == 0) {
            int t0 = tg[bL];
            pathf[b] = pacc + st[t0] + em[base + t0];
        }

#pragma unroll
        for (int k = 0; k < 4; ++k) Mlds[l + 64 * k] = mask[bL + l + 64 * k];

        // B-fragments, sigma-permuted: byte e of k-group h = state
        // sigma(h,e) = 32h + (e>>1) + 16*(e&1). Quad dd covers states
        // {32h+2dd, 32h+16+2dd, 32h+2dd+1, 32h+17+2dd} (cols j = 16jt + c).
        v8i_t Bf[8];
#pragma unroll
        for (int jt = 0; jt < 8; ++jt) {
            v8i_t bb;
#pragma unroll
            for (int dd = 0; dd < 8; ++dd) {
                const float* p = trans + (size_t)(32 * h + 2 * dd) * N_ + 16 * jt + c;
                float f0 = __expf(p[0]);           // state 32h+2dd
                float f1 = __expf(p[16 * N_]);     // state 32h+16+2dd
                float f2 = __expf(p[N_]);          // state 32h+2dd+1
                float f3 = __expf(p[17 * N_]);     // state 32h+17+2dd
                bb[dd] = (int)fp8_quad(f0, f1, f2, f3);
            }
            Bf[jt] = bb;
        }

        // init alpha_0
        float ns0 = st[s0] + em[base + s0];
        float ns1 = st[s1] + em[base + s1];
        float Mprev = wave_max(fmaxf(ns0, ns1));
        {
            unsigned p = fp8_pair(__expf(ns0 - Mprev - C_BIAS), __expf(ns1 - Mprev - C_BIAS));
            *(unsigned short*)(Eh + 2 * l) = (unsigned short)p;
        }
        v8i_t Af = *(const v8i_t*)(Eh + 32 * h);   // A-frag for step 1

        float pa0 = em[base + (size_t)1 * N_ + s0], pb0 = em[base + (size_t)1 * N_ + s1];
        float pa1 = em[base + (size_t)2 * N_ + s0], pb1 = em[base + (size_t)2 * N_ + s1];
        float pa2 = em[base + (size_t)3 * N_ + s0], pb2 = em[base + (size_t)3 * N_ + s1];
        float pa3 = em[base + (size_t)4 * N_ + s0], pb3 = em[base + (size_t)4 * N_ + s1];

        auto step = [&](int t, float& sa, float& sb) {
            float emv0 = sa, emv1 = sb;
            int tpf = t + 4; if (tpf > TM - 1) tpf = TM - 1;
            sa = em[base + (size_t)tpf * N_ + s0];
            sb = em[base + (size_t)tpf * N_ + s1];
            float mk = Mlds[t];

            float mx = wave_max(fmaxf(ns0, ns1));   // max(ns_{t-1}); overlaps read

            v8i_t Afrag = Af;                       // carried early read
            f4_t z = {0.f, 0.f, 0.f, 0.f};
            MXMFMA(q0, Bf[0]) MXMFMA(q1, Bf[1]) MXMFMA(q2, Bf[2]) MXMFMA(q3, Bf[3])
            MXMFMA(q4, Bf[4]) MXMFMA(q5, Bf[5]) MXMFMA(q6, Bf[6]) MXMFMA(q7, Bf[7])

            // in-register pickup of owned states (replicated D rows, reg 0)
            float sv0 = hb1 ? (hb0 ? q6[0] : q4[0]) : (hb0 ? q2[0] : q0[0]);
            float sv1 = hb1 ? (hb0 ? q7[0] : q5[0]) : (hb0 ? q3[0] : q1[0]);

            float badd = Mprev + C_BIAS;
            float nxt0 = __logf(sv0) + badd + emv0;
            float nxt1 = __logf(sv1) + badd + emv1;
            float im = 1.f - mk;
            ns0 = mk * nxt0 + im * ns0;
            ns1 = mk * nxt1 + im * ns1;

            Mprev = mx;
            unsigned p = fp8_pair(__expf(ns0 - mx - C_BIAS), __expf(ns1 - mx - C_BIAS));
            *(unsigned short*)(Eh + 2 * l) = (unsigned short)p;
            Af = *(const v8i_t*)(Eh + 32 * h);      // early read for step t+1
        };

        for (int tt = 1; tt + 3 < TM; tt += 4) {
            step(tt    , pa0, pb0);
            step(tt + 1, pa1, pb1);
            step(tt + 2, pa2, pb2);
            step(tt + 3, pa3, pb3);
        }
        step(TM - 3, pa0, pb0);
        step(TM - 2, pa1, pb1);
        step(TM - 1, pa2, pb2);

        alpha[b * N_ + s0] = ns0;
        alpha[b * N_ + s1] = ns1;
    } else {
        // ================= BACKWARD =================
        // path-score half: t in [TM, L)
        float pacc = 0.f;
        for (int t = TM + l; t < L_; t += 64) {
            int cur  = tg[bL + t];
            int prev = tg[bL + t - 1];
            pacc += mask[bL + t] * (trans[prev * N_ + cur] + em[base + (size_t)t * N_ + cur]);
        }
        pacc = wave_sum(pacc);
        if (l == 0) pathb[b] = pacc;

#pragma unroll
        for (int k = 0; k < 4; ++k) Mlds[l + 64 * k] = mask[bL + TM + l + 64 * k];

        // B-fragments, sigma-permuted: byte e = exp(trans[16it + c][sigma(h,e)])
        v8i_t Bf[8];
#pragma unroll
        for (int it = 0; it < 8; ++it) {
            v8i_t bb;
#pragma unroll
            for (int dd = 0; dd < 8; ++dd) {
                const float* p = trans + (size_t)(16 * it + c) * N_ + 32 * h + 2 * dd;
                float f0 = __expf(p[0]);    // col 32h+2dd
                float f1 = __expf(p[16]);   // col 32h+16+2dd
                float f2 = __expf(p[1]);    // col 32h+2dd+1
                float f3 = __expf(p[17]);   // col 32h+17+2dd
                bb[dd] = (int)fp8_quad(f0, f1, f2, f3);
            }
            Bf[it] = bb;
        }

        // init at u=511: beta_511 = 0 ; v = beta + em_511
        float b0 = 0.f, b1 = 0.f;
        float v0 = em[base + (size_t)(L_ - 1) * N_ + s0];
        float v1 = em[base + (size_t)(L_ - 1) * N_ + s1];
        float Mprev = wave_max(fmaxf(v0, v1));
        {
            unsigned p = fp8_pair(__expf(v0 - Mprev - C_BIAS), __expf(v1 - Mprev - C_BIAS));
            *(unsigned short*)(Eh + 2 * l) = (unsigned short)p;
        }
        v8i_t Af = *(const v8i_t*)(Eh + 32 * h);

        float pa0 = em[base + (size_t)510 * N_ + s0], pb0 = em[base + (size_t)510 * N_ + s1];
        float pa1 = em[base + (size_t)509 * N_ + s0], pb1 = em[base + (size_t)509 * N_ + s1];
        float pa2 = em[base + (size_t)508 * N_ + s0], pb2 = em[base + (size_t)508 * N_ + s1];
        float pa3 = em[base + (size_t)507 * N_ + s0], pb3 = em[base + (size_t)507 * N_ + s1];

        // iter t (510 down to 255): consumes F_{t+1} (Eh), em_t (pipe), mask_{t+1}
        auto step = [&](int t, float& sa, float& sb) {
            float emt0 = sa, emt1 = sb;
            int tpf = t - 4; if (tpf < TM - 1) tpf = TM - 1;
            sa = em[base + (size_t)tpf * N_ + s0];
            sb = em[base + (size_t)tpf * N_ + s1];
            float mk = Mlds[t + 1 - TM];

            float mx = wave_max(fmaxf(v0, v1));   // max(v_{t+1}); overlaps read

            v8i_t Afrag = Af;                     // carried early read
            f4_t z = {0.f, 0.f, 0.f, 0.f};
            MXMFMA(q0, Bf[0]) MXMFMA(q1, Bf[1]) MXMFMA(q2, Bf[2]) MXMFMA(q3, Bf[3])
            MXMFMA(q4, Bf[4]) MXMFMA(q5, Bf[5]) MXMFMA(q6, Bf[6]) MXMFMA(q7, Bf[7])

            float sv0 = hb1 ? (hb0 ? q6[0] : q4[0]) : (hb0 ? q2[0] : q0[0]);
            float sv1 = hb1 ? (hb0 ? q7[0] : q5[0]) : (hb0 ? q3[0] : q1[0]);

            float badd = Mprev + C_BIAS;
            float upd0 = __logf(sv0) + badd;
            float upd1 = __logf(sv1) + badd;
            float im = 1.f - mk;
            b0 = mk * upd0 + im * b0;
            b1 = mk * upd1 + im * b1;

            v0 = b0 + emt0;
            v1 = b1 + emt1;
            Mprev = mx;
            unsigned p = fp8_pair(__expf(v0 - mx - C_BIAS), __expf(v1 - mx - C_BIAS));
            *(unsigned short*)(Eh + 2 * l) = (unsigned short)p;
            Af = *(const v8i_t*)(Eh + 32 * h);    // early read for next step
        };

        for (int tt = 510; tt >= 258; tt -= 4) {   // 64 groups x 4 = t 510..255
            step(tt    , pa0, pb0);
            step(tt - 1, pa1, pb1);
            step(tt - 2, pa2, pb2);
            step(tt - 3, pa3, pb3);
        }

        beta[b * N_ + s0] = b0;
        beta[b * N_ + s1] = b1;
    }
}

// ---------------------------------------------------------------------------
// zres_kernel: 512 blocks x 1 wave. Block b: zres[b] = LSE_j(alpha[j]+beta[j])
//              - pathf[b] - pathb[b].
// ---------------------------------------------------------------------------
__global__ __launch_bounds__(64) void zres_kernel(
    const float* __restrict__ alpha, const float* __restrict__ beta,
    const float* __restrict__ pathf, const float* __restrict__ pathb,
    float* __restrict__ zres)
{
    const int l = threadIdx.x;
    const int b = blockIdx.x;
    float2 av = *(const float2*)(alpha + b * N_ + 2 * l);
    float2 bv = *(const float2*)(beta  + b * N_ + 2 * l);
    float v0 = av.x + bv.x;
    float v1 = av.y + bv.y;
    float m = wave_max(fmaxf(v0, v1));
    float s = wave_sum(__expf(v0 - m) + __expf(v1 - m));
    if (l == 0) zres[b] = m + __logf(s) - pathf[b] - pathb[b];
}

// ---------------------------------------------------------------------------
// mean_kernel: 1 wave. out = mean(zres). 8 values/lane (2x float4) + DPP tree.
// ---------------------------------------------------------------------------
__global__ __launch_bounds__(64) void mean_kernel(
    const float* __restrict__ zres, float* __restrict__ out)
{
    const int l = threadIdx.x;
    const float4* z4 = (const float4*)zres;
    float4 a = z4[2 * l];
    float4 c = z4[2 * l + 1];
    float acc = ((a.x + a.y) + (a.z + a.w)) + ((c.x + c.y) + (c.z + c.w));
    acc = wave_sum(acc);
    if (l == 0) out[0] = acc * (1.0f / (float)B_);
}

// ---------------------------------------------------------------------------
extern "C" void kernel_launch(void* const* d_in, const int* in_sizes, int n_in,
                              void* d_out, int out_size, void* d_ws, size_t ws_size,
                              hipStream_t stream) {
    const float* emission    = (const float*)d_in[0];
    const int*   target      = (const int*)  d_in[1];
    const float* mask        = (const float*)d_in[2];
    const float* start_trans = (const float*)d_in[3];
    const float* trans       = (const float*)d_in[4];
    float* out = (float*)d_out;

    float* ws_f  = (float*)d_ws;
    float* alpha = ws_f;                        // 512*128
    float* beta  = ws_f + B_ * N_;              // 512*128
    float* pathf = ws_f + 2 * B_ * N_;          // 512
    float* pathb = ws_f + 2 * B_ * N_ + B_;     // 512
    float* zres  = ws_f + 2 * B_ * N_ + 2 * B_; // 512

    norm_kernel<<<2 * B_, 64, 0, stream>>>(emission, target, mask, start_trans,
                                           trans, alpha, beta, pathf, pathb);
    zres_kernel<<<B_, 64, 0, stream>>>(alpha, beta, pathf, pathb, zres);
    mean_kernel<<<1, 64, 0, stream>>>(zres, out);
}